// Round 3
// baseline (655.444 us; speedup 1.0000x reference)
//
#include <hip/hip_runtime.h>
#include <hip/hip_bf16.h>

// Problem constants
#define B_    65536
#define A_    8
#define S_    128
#define ADIM_ 16
#define H_    64
#define IN_   144
#define H3_   192
#define NROW  (B_*A_)   // 524288

typedef __attribute__((ext_vector_type(8))) short bf16x8;
typedef __attribute__((ext_vector_type(4))) float f32x4;

// ---- packed weight fragment table (bf16, MFMA A-operand layout) ----
// frag = 64 lanes x 8 bf16 = 1024 B. lane l holds W[k][n] for
// k = kt*32 + (l>>4)*8 + i, n = mt*16 + (l&15).
#define F_ENC 20   // kt 0..4, mt 0..3
#define F_OBS 8    // kt 0..1, mt 0..3
#define F_WI  24   // kt 0..1, mt 0..11
#define F_WH  24
#define OFF_ENC 0
#define OFF_OBS (F_ENC)
#define OFF_WI  (F_ENC+F_OBS)
#define OFF_WH  (F_ENC+F_OBS+F_WI)
#define NFRAG   (F_ENC+F_OBS+F_WI+F_WH)  // 76
#define BIAS_OFF (NFRAG*512)             // in shorts; 256 floats follow
// bias layout (floats): [0..127] bi+bh (r,z)   [128..191] bi_n   [192..255] bh_n

__device__ __forceinline__ short f2bf_s(float f){
  union { __hip_bfloat16 b; short s; } u;
  u.b = __float2bfloat16(f);            // compiler pairs into v_cvt_pk_bf16_f32
  return u.s;
}
__device__ __forceinline__ unsigned pk2(float lo, float hi){
  return (unsigned)(unsigned short)f2bf_s(lo) | ((unsigned)(unsigned short)f2bf_s(hi) << 16);
}
__device__ __forceinline__ float bf2f(unsigned short s){
  union{float f; unsigned u;} v; v.u = ((unsigned)s)<<16; return v.f;
}
__device__ __forceinline__ float sigmoidf_(float x){
  float e = __expf(-x);
  return __builtin_amdgcn_rcpf(1.f + e);
}
__device__ __forceinline__ float tanhf_(float x){
  float e = __expf(2.f*x);
  return 1.f - 2.f*__builtin_amdgcn_rcpf(e + 1.f);
}
__device__ __forceinline__ f32x4 MFMA(bf16x8 a, bf16x8 b, f32x4 c){
  return __builtin_amdgcn_mfma_f32_16x16x32_bf16(a, b, c, 0, 0, 0);
}
__device__ __forceinline__ f32x4 zero4(){ f32x4 v; v[0]=v[1]=v[2]=v[3]=0.f; return v; }

// ---------------- weight/bias pre-pack kernel (runs every launch) --------
__global__ __launch_bounds__(64) void pack_weights(
    const float* __restrict__ We, const float* __restrict__ Wo,
    const float* __restrict__ Wi, const float* __restrict__ Wh,
    const float* __restrict__ bi, const float* __restrict__ bh,
    unsigned short* __restrict__ pw)
{
  int f = blockIdx.x, lane = threadIdx.x;
  if (f == NFRAG){            // combined-bias block
    float* fb = (float*)(pw + BIAS_OFF);
#pragma unroll
    for (int i=0;i<4;i++){
      int idx = lane*4 + i;
      float v;
      if (idx < 128)       v = bi[idx] + bh[idx];        // r,z combined
      else if (idx < 192)  v = bi[idx];                  // 128..191 = bi_n
      else                 v = bh[idx - 64];             // 192..255 = bh[128..191]
      fb[idx] = v;
    }
    return;
  }
  const float* W; int K, NC, kt, mt;
  if (f < OFF_OBS)      { W=We; K=IN_; NC=H_;  int fi=f;         kt=fi>>2;  mt=fi&3;  }
  else if (f < OFF_WI)  { W=Wo; K=H_;  NC=H_;  int fi=f-OFF_OBS; kt=fi>>2;  mt=fi&3;  }
  else if (f < OFF_WH)  { W=Wi; K=H_;  NC=H3_; int fi=f-OFF_WI;  kt=fi/12;  mt=fi%12; }
  else                  { W=Wh; K=H_;  NC=H3_; int fi=f-OFF_WH;  kt=fi/12;  mt=fi%12; }
  int g = lane>>4, l15 = lane&15;
  bf16x8 v;
#pragma unroll
  for (int i=0;i<8;i++){
    int k = kt*32 + g*8 + i;
    int n = mt*16 + l15;
    float x = (k < K) ? W[(size_t)k*NC + n] : 0.f;
    v[i] = f2bf_s(x);
  }
  *(bf16x8*)(pw + (size_t)f*512 + lane*8) = v;
}

// ---------------- fused critic kernel -----------------------------------
// 256 thr = 4 waves; each wave owns 32 rows (2 MFMA tiles of 16 rows = 2x2
// complete agent batches). GEMMs computed transposed (D^T = W^T x^T) so the
// GRU elementwise is lane-local; GEMM->GEMM re-layout via per-wave LDS buf.
// __launch_bounds__(256,4): 4 waves/SIMD; register budget 128 must be met
// WITHOUT spills (round-2 lesson: 722 MB scratch writes when it isn't).
__global__ __launch_bounds__(256, 4) void critic_main(
    const float* __restrict__ obs, const float* __restrict__ act,
    const float* __restrict__ b_enc, const float* __restrict__ b_obs,
    const float* __restrict__ wdec,  const float* __restrict__ bdec,
    const unsigned short* __restrict__ pw, float* __restrict__ out)
{
  // single per-(wave,u) buffer: wave-lockstep + in-order DS make RAW/WAR safe
  __shared__ unsigned short buf[4][2][16*72];
  __shared__ float Sbuf[4][2][2][64];   // [wave][u][batch-in-tile][feature]

  const int tid = threadIdx.x, wid = tid>>6, lane = tid&63;
  const int g = lane>>4, l15 = lane&15;
  const size_t rb = ((size_t)blockIdx.x*4 + wid)*32;
  const bf16x8* pf = (const bf16x8*)pw;
  const float*  bc = (const float*)(pw + BIAS_OFF);

  const f32x4* po[2];
#pragma unroll
  for (int u=0;u<2;u++) po[u] = (const f32x4*)(obs + (rb + u*16 + l15)*S_);

  // ======== Stage E: e = relu([obs|act] @ W_enc + b_enc) ========
  // depth-1 software pipeline on the x loads: 32 regs in flight max.
  f32x4 acc[2][4];
#pragma unroll
  for (int u=0;u<2;u++)
#pragma unroll
    for (int mt=0;mt<4;mt++) acc[u][mt] = zero4();

  f32x4 xa[2][2], xn[2][2];
#pragma unroll
  for (int u=0;u<2;u++){ xa[u][0] = po[u][g*2]; xa[u][1] = po[u][g*2+1]; }

#pragma unroll
  for (int kt=0; kt<5; kt++){
    if (kt < 3){
#pragma unroll
      for (int u=0;u<2;u++){
        xn[u][0] = po[u][(kt+1)*8 + g*2];
        xn[u][1] = po[u][(kt+1)*8 + g*2 + 1];
      }
    } else if (kt == 3){
#pragma unroll
      for (int u=0;u<2;u++){
        if (g < 2){
          const f32x4* pa = (const f32x4*)(act + (rb + u*16 + l15)*ADIM_ + g*8);
          xn[u][0] = pa[0]; xn[u][1] = pa[1];
        } else {
          xn[u][0] = zero4(); xn[u][1] = zero4();
        }
      }
    }
    bf16x8 xf[2];
#pragma unroll
    for (int u=0;u<2;u++){
      bf16x8 t;
#pragma unroll
      for (int i=0;i<4;i++){ t[i] = f2bf_s(xa[u][0][i]); t[i+4] = f2bf_s(xa[u][1][i]); }
      xf[u] = t;
    }
#pragma unroll
    for (int mt=0;mt<4;mt++){
      bf16x8 wf = pf[(OFF_ENC + kt*4 + mt)*64 + lane];
      acc[0][mt] = MFMA(wf, xf[0], acc[0][mt]);
      acc[1][mt] = MFMA(wf, xf[1], acc[1][mt]);
    }
#pragma unroll
    for (int u=0;u<2;u++){ xa[u][0] = xn[u][0]; xa[u][1] = xn[u][1]; }
  }

  // relu+bias, stage e into LDS (row-major [16][72] bf16 per u)
#pragma unroll
  for (int mt=0;mt<4;mt++){
    f32x4 be = *(const f32x4*)(b_enc + mt*16 + g*4);
#pragma unroll
    for (int u=0;u<2;u++){
      uint2 pk;
      pk.x = pk2(fmaxf(acc[u][mt][0]+be[0],0.f), fmaxf(acc[u][mt][1]+be[1],0.f));
      pk.y = pk2(fmaxf(acc[u][mt][2]+be[2],0.f), fmaxf(acc[u][mt][3]+be[3],0.f));
      *(uint2*)(&buf[wid][u][l15*72 + mt*16 + g*4]) = pk;
    }
  }
  __threadfence_block();

  // ======== Stage O: h0 = e @ W_obs + b_obs, written to LDS as bf16 ======
  {
    bf16x8 ef[2][2];
#pragma unroll
    for (int u=0;u<2;u++)
#pragma unroll
      for (int kt=0;kt<2;kt++)
        ef[u][kt] = *(const bf16x8*)(&buf[wid][u][l15*72 + kt*32 + g*8]);
    f32x4 h0[2][4];
#pragma unroll
    for (int u=0;u<2;u++)
#pragma unroll
      for (int mt=0;mt<4;mt++) h0[u][mt] = zero4();
#pragma unroll
    for (int kt=0;kt<2;kt++)
#pragma unroll
      for (int mt=0;mt<4;mt++){
        bf16x8 wf = pf[(OFF_OBS + kt*4 + mt)*64 + lane];
        h0[0][mt] = MFMA(wf, ef[0][kt], h0[0][mt]);
        h0[1][mt] = MFMA(wf, ef[1][kt], h0[1][mt]);
      }
#pragma unroll
    for (int mt=0;mt<4;mt++){
      f32x4 bo = *(const f32x4*)(b_obs + mt*16 + g*4);
#pragma unroll
      for (int u=0;u<2;u++){
        uint2 pk;
        pk.x = pk2(h0[u][mt][0]+bo[0], h0[u][mt][1]+bo[1]);
        pk.y = pk2(h0[u][mt][2]+bo[2], h0[u][mt][3]+bo[3]);
        *(uint2*)(&buf[wid][u][l15*72 + mt*16 + g*4]) = pk;
      }
    }
  }
  __threadfence_block();

  // ======== GRU step 1 (c = 0): gi = bi; h0 re-read from LDS (bf16) ======
  {
    bf16x8 hf[2][2];
#pragma unroll
    for (int u=0;u<2;u++)
#pragma unroll
      for (int kt=0;kt<2;kt++)
        hf[u][kt] = *(const bf16x8*)(&buf[wid][u][l15*72 + kt*32 + g*8]);
#pragma unroll
    for (int mt=0;mt<4;mt++){
      f32x4 brz_r = *(const f32x4*)(bc +       mt*16 + g*4);
      f32x4 brz_z = *(const f32x4*)(bc + 64  + mt*16 + g*4);
      f32x4 bin   = *(const f32x4*)(bc + 128 + mt*16 + g*4);
      f32x4 bhn   = *(const f32x4*)(bc + 192 + mt*16 + g*4);
      f32x4 gr[2], gz[2], gn[2];
#pragma unroll
      for (int u=0;u<2;u++){ gr[u]=zero4(); gz[u]=zero4(); gn[u]=zero4(); }
#pragma unroll
      for (int kt=0;kt<2;kt++){
        bf16x8 wr_ = pf[(OFF_WH + kt*12 + mt    )*64 + lane];
        bf16x8 wz_ = pf[(OFF_WH + kt*12 + mt + 4)*64 + lane];
        bf16x8 wn_ = pf[(OFF_WH + kt*12 + mt + 8)*64 + lane];
#pragma unroll
        for (int u=0;u<2;u++){
          gr[u] = MFMA(wr_, hf[u][kt], gr[u]);
          gz[u] = MFMA(wz_, hf[u][kt], gz[u]);
          gn[u] = MFMA(wn_, hf[u][kt], gn[u]);
        }
      }
#pragma unroll
      for (int u=0;u<2;u++){
        uint2 q = *(const uint2*)(&buf[wid][u][l15*72 + mt*16 + g*4]);  // h0 bf16
        float h0v[4];
        h0v[0] = bf2f((unsigned short)(q.x & 0xffff));
        h0v[1] = bf2f((unsigned short)(q.x >> 16));
        h0v[2] = bf2f((unsigned short)(q.y & 0xffff));
        h0v[3] = bf2f((unsigned short)(q.y >> 16));
        f32x4 h1;
#pragma unroll
        for (int j=0;j<4;j++){
          float r = sigmoidf_(gr[u][j] + brz_r[j]);
          float z = sigmoidf_(gz[u][j] + brz_z[j]);
          float n = tanhf_(bin[j] + r*(gn[u][j] + bhn[j]));
          h1[j] = (1.f - z)*n + z*h0v[j];
        }
        uint2 pk;                      // overwrite with h1 (hf reads done)
        pk.x = pk2(h1[0], h1[1]);
        pk.y = pk2(h1[2], h1[3]);
        *(uint2*)(&buf[wid][u][l15*72 + mt*16 + g*4]) = pk;
      }
    }
  }
  __threadfence_block();

  // ======== agent mix: per-batch column sums -> c = (S - h1)/8 ========
#pragma unroll
  for (int u=0;u<2;u++){
    int b = lane>>5;
#pragma unroll
    for (int rep=0;rep<2;rep++){
      int c = (lane&31) + rep*32;
      float s = 0.f;
#pragma unroll
      for (int r=0;r<8;r++) s += bf2f(buf[wid][u][(b*8+r)*72 + c]);
      Sbuf[wid][u][b][c] = s;
    }
  }
  __threadfence_block();

  bf16x8 hf2[2][2], cf[2][2];
#pragma unroll
  for (int u=0;u<2;u++)
#pragma unroll
    for (int kt=0;kt<2;kt++){
      bf16x8 h8 = *(const bf16x8*)(&buf[wid][u][l15*72 + kt*32 + g*8]);
      hf2[u][kt] = h8;
      f32x4 s0 = *(const f32x4*)(&Sbuf[wid][u][l15>>3][kt*32 + g*8]);
      f32x4 s1 = *(const f32x4*)(&Sbuf[wid][u][l15>>3][kt*32 + g*8 + 4]);
      bf16x8 c8;
#pragma unroll
      for (int i=0;i<4;i++){
        c8[i]   = f2bf_s((s0[i] - bf2f((unsigned short)h8[i]  )) * 0.125f);
        c8[i+4] = f2bf_s((s1[i] - bf2f((unsigned short)h8[i+4])) * 0.125f);
      }
      cf[u][kt] = c8;
    }

  // ======== GRU step 2 + fused decode ========
  float p[2]; p[0]=0.f; p[1]=0.f;
#pragma unroll
  for (int mt=0;mt<4;mt++){
    f32x4 brz_r = *(const f32x4*)(bc +       mt*16 + g*4);
    f32x4 brz_z = *(const f32x4*)(bc + 64  + mt*16 + g*4);
    f32x4 bin   = *(const f32x4*)(bc + 128 + mt*16 + g*4);
    f32x4 bhn   = *(const f32x4*)(bc + 192 + mt*16 + g*4);
    f32x4 wdv   = *(const f32x4*)(wdec + mt*16 + g*4);
    f32x4 gr[2], gz[2], gni[2], gnh[2];
#pragma unroll
    for (int u=0;u<2;u++){ gr[u]=zero4(); gz[u]=zero4(); gni[u]=zero4(); gnh[u]=zero4(); }
#pragma unroll
    for (int kt=0;kt<2;kt++){
      bf16x8 whr = pf[(OFF_WH + kt*12 + mt    )*64 + lane];
      bf16x8 whz = pf[(OFF_WH + kt*12 + mt + 4)*64 + lane];
      bf16x8 whn = pf[(OFF_WH + kt*12 + mt + 8)*64 + lane];
      bf16x8 wir = pf[(OFF_WI + kt*12 + mt    )*64 + lane];
      bf16x8 wiz = pf[(OFF_WI + kt*12 + mt + 4)*64 + lane];
      bf16x8 win = pf[(OFF_WI + kt*12 + mt + 8)*64 + lane];
#pragma unroll
      for (int u=0;u<2;u++){
        gr[u]  = MFMA(whr, hf2[u][kt], gr[u]);
        gr[u]  = MFMA(wir, cf[u][kt],  gr[u]);
        gz[u]  = MFMA(whz, hf2[u][kt], gz[u]);
        gz[u]  = MFMA(wiz, cf[u][kt],  gz[u]);
        gnh[u] = MFMA(whn, hf2[u][kt], gnh[u]);
        gni[u] = MFMA(win, cf[u][kt],  gni[u]);
      }
    }
#pragma unroll
    for (int u=0;u<2;u++){
      uint2 q = *(const uint2*)(&buf[wid][u][l15*72 + mt*16 + g*4]);  // h1 bf16
      float h1v[4];
      h1v[0] = bf2f((unsigned short)(q.x & 0xffff));
      h1v[1] = bf2f((unsigned short)(q.x >> 16));
      h1v[2] = bf2f((unsigned short)(q.y & 0xffff));
      h1v[3] = bf2f((unsigned short)(q.y >> 16));
#pragma unroll
      for (int j=0;j<4;j++){
        float r = sigmoidf_(gr[u][j] + brz_r[j]);
        float z = sigmoidf_(gz[u][j] + brz_z[j]);
        float n = tanhf_(gni[u][j] + bin[j] + r*(gnh[u][j] + bhn[j]));
        float h2 = (1.f - z)*n + z*h1v[j];
        p[u] += h2 * wdv[j];            // fused decode
      }
    }
  }

  // ======== decode reduce + store ========
  float bd = bdec[0];
#pragma unroll
  for (int u=0;u<2;u++){
    float v = p[u];
    v += __shfl_xor(v, 16, 64);
    v += __shfl_xor(v, 32, 64);
    if (lane < 16) out[rb + u*16 + l15] = v + bd;
  }
}

// ---------------- launch ----------------
extern "C" void kernel_launch(void* const* d_in, const int* in_sizes, int n_in,
                              void* d_out, int out_size, void* d_ws, size_t ws_size,
                              hipStream_t stream) {
  (void)in_sizes; (void)n_in; (void)out_size; (void)ws_size;
  const float* obs   = (const float*)d_in[0];
  const float* act   = (const float*)d_in[1];
  const float* W_enc = (const float*)d_in[2];
  const float* b_enc = (const float*)d_in[3];
  const float* W_obs = (const float*)d_in[4];
  const float* b_obs = (const float*)d_in[5];
  const float* Wi    = (const float*)d_in[6];
  const float* bi    = (const float*)d_in[7];
  const float* Wh    = (const float*)d_in[8];
  const float* bh    = (const float*)d_in[9];
  const float* wdec  = (const float*)d_in[10];
  const float* bdec  = (const float*)d_in[11];
  unsigned short* pw = (unsigned short*)d_ws;   // 76 KiB frags + 1 KiB biases

  hipLaunchKernelGGL(pack_weights, dim3(NFRAG+1), dim3(64), 0, stream,
                     W_enc, W_obs, Wi, Wh, bi, bh, pw);
  hipLaunchKernelGGL(critic_main, dim3(NROW/128), dim3(256), 0, stream,
                     obs, act, b_enc, b_obs, wdec, bdec, pw, (float*)d_out);
}

// Round 5
// 537.927 us; speedup vs baseline: 1.2185x; 1.2185x over previous
//
#include <hip/hip_runtime.h>
#include <hip/hip_bf16.h>

// Problem constants
#define B_    65536
#define A_    8
#define S_    128
#define ADIM_ 16
#define H_    64
#define IN_   144
#define H3_   192
#define NROW  (B_*A_)   // 524288

typedef __attribute__((ext_vector_type(8))) short bf16x8;
typedef __attribute__((ext_vector_type(4))) float f32x4;

// ---- packed weight fragment table (bf16, MFMA A-operand layout) ----
// frag = 64 lanes x 8 bf16 = 1024 B. lane l holds W[k][n] for
// k = kt*32 + (l>>4)*8 + i, n = mt*16 + (l&15).
#define F_ENC 20   // kt 0..4, mt 0..3
#define F_OBS 8    // kt 0..1, mt 0..3
#define F_WI  24   // kt 0..1, mt 0..11
#define F_WH  24
#define OFF_ENC 0
#define OFF_OBS (F_ENC)
#define OFF_WI  (F_ENC+F_OBS)
#define OFF_WH  (F_ENC+F_OBS+F_WI)
#define NFRAG   (F_ENC+F_OBS+F_WI+F_WH)  // 76
#define BIAS_OFF (NFRAG*512)             // in shorts; 256 floats follow
// bias layout (floats): [0..127] bi+bh (r,z)   [128..191] bi_n   [192..255] bh_n

__device__ __forceinline__ short f2bf_s(float f){
  union { __hip_bfloat16 b; short s; } u;
  u.b = __float2bfloat16(f);            // compiler pairs into v_cvt_pk_bf16_f32
  return u.s;
}
__device__ __forceinline__ unsigned pk2(float lo, float hi){
  return (unsigned)(unsigned short)f2bf_s(lo) | ((unsigned)(unsigned short)f2bf_s(hi) << 16);
}
__device__ __forceinline__ float bf2f(unsigned short s){
  union{float f; unsigned u;} v; v.u = ((unsigned)s)<<16; return v.f;
}
__device__ __forceinline__ float sigmoidf_(float x){
  float e = __expf(-x);
  return __builtin_amdgcn_rcpf(1.f + e);
}
__device__ __forceinline__ float tanhf_(float x){
  float e = __expf(2.f*x);
  return 1.f - 2.f*__builtin_amdgcn_rcpf(e + 1.f);
}
__device__ __forceinline__ f32x4 MFMA(bf16x8 a, bf16x8 b, f32x4 c){
  return __builtin_amdgcn_mfma_f32_16x16x32_bf16(a, b, c, 0, 0, 0);
}
__device__ __forceinline__ f32x4 zero4(){ f32x4 v; v[0]=v[1]=v[2]=v[3]=0.f; return v; }

// ---------------- weight/bias pre-pack kernel (runs every launch) --------
__global__ __launch_bounds__(64) void pack_weights(
    const float* __restrict__ We, const float* __restrict__ Wo,
    const float* __restrict__ Wi, const float* __restrict__ Wh,
    const float* __restrict__ bi, const float* __restrict__ bh,
    unsigned short* __restrict__ pw)
{
  int f = blockIdx.x, lane = threadIdx.x;
  if (f == NFRAG){            // combined-bias block
    float* fb = (float*)(pw + BIAS_OFF);
#pragma unroll
    for (int i=0;i<4;i++){
      int idx = lane*4 + i;
      float v;
      if (idx < 128)       v = bi[idx] + bh[idx];        // r,z combined
      else if (idx < 192)  v = bi[idx];                  // 128..191 = bi_n
      else                 v = bh[idx - 64];             // 192..255 = bh[128..191]
      fb[idx] = v;
    }
    return;
  }
  const float* W; int K, NC, kt, mt;
  if (f < OFF_OBS)      { W=We; K=IN_; NC=H_;  int fi=f;         kt=fi>>2;  mt=fi&3;  }
  else if (f < OFF_WI)  { W=Wo; K=H_;  NC=H_;  int fi=f-OFF_OBS; kt=fi>>2;  mt=fi&3;  }
  else if (f < OFF_WH)  { W=Wi; K=H_;  NC=H3_; int fi=f-OFF_WI;  kt=fi/12;  mt=fi%12; }
  else                  { W=Wh; K=H_;  NC=H3_; int fi=f-OFF_WH;  kt=fi/12;  mt=fi%12; }
  int g = lane>>4, l15 = lane&15;
  bf16x8 v;
#pragma unroll
  for (int i=0;i<8;i++){
    int k = kt*32 + g*8 + i;
    int n = mt*16 + l15;
    float x = (k < K) ? W[(size_t)k*NC + n] : 0.f;
    v[i] = f2bf_s(x);
  }
  *(bf16x8*)(pw + (size_t)f*512 + lane*8) = v;
}

// ---------------- fused critic kernel -----------------------------------
// 256 thr = 4 waves; each wave owns 32 rows (2 MFMA tiles of 16 rows = 2x2
// complete agent batches). GEMMs computed transposed (D^T = W^T x^T) so the
// GRU elementwise is lane-local; GEMM->GEMM re-layout via per-wave LDS buf.
// __launch_bounds__(256,3): budget ~170 regs/wave. Round-2/3 lesson: at
// (256,4) the allocator splits 64 arch + 64 AGPR and spills ~650 MB of
// scratch to HBM; at (256,3) the round-1-sized working set fits spill-free.
__global__ __launch_bounds__(256, 3) void critic_main(
    const float* __restrict__ obs, const float* __restrict__ act,
    const float* __restrict__ b_enc, const float* __restrict__ b_obs,
    const float* __restrict__ wdec,  const float* __restrict__ bdec,
    const unsigned short* __restrict__ pw, float* __restrict__ out)
{
  // single per-(wave,u) buffer: wave-lockstep + in-order DS make RAW/WAR safe
  __shared__ unsigned short buf[4][2][16*72];
  __shared__ float Sbuf[4][2][2][64];   // [wave][u][batch-in-tile][feature]

  const int tid = threadIdx.x, wid = tid>>6, lane = tid&63;
  const int g = lane>>4, l15 = lane&15;
  const size_t rb = ((size_t)blockIdx.x*4 + wid)*32;
  const bf16x8* pf = (const bf16x8*)pw;
  const float*  bc = (const float*)(pw + BIAS_OFF);

  const f32x4* po[2];
#pragma unroll
  for (int u=0;u<2;u++) po[u] = (const f32x4*)(obs + (rb + u*16 + l15)*S_);

  // ======== Stage E: e = relu([obs|act] @ W_enc + b_enc) ========
  // depth-1 software pipeline on the x loads: 32 regs in flight max.
  f32x4 acc[2][4];
#pragma unroll
  for (int u=0;u<2;u++)
#pragma unroll
    for (int mt=0;mt<4;mt++) acc[u][mt] = zero4();

  f32x4 xa[2][2], xn[2][2];
#pragma unroll
  for (int u=0;u<2;u++){ xa[u][0] = po[u][g*2]; xa[u][1] = po[u][g*2+1]; }

#pragma unroll
  for (int kt=0; kt<5; kt++){
    if (kt < 3){
#pragma unroll
      for (int u=0;u<2;u++){
        xn[u][0] = po[u][(kt+1)*8 + g*2];
        xn[u][1] = po[u][(kt+1)*8 + g*2 + 1];
      }
    } else if (kt == 3){
#pragma unroll
      for (int u=0;u<2;u++){
        if (g < 2){
          const f32x4* pa = (const f32x4*)(act + (rb + u*16 + l15)*ADIM_ + g*8);
          xn[u][0] = pa[0]; xn[u][1] = pa[1];
        } else {
          xn[u][0] = zero4(); xn[u][1] = zero4();
        }
      }
    }
    bf16x8 xf[2];
#pragma unroll
    for (int u=0;u<2;u++){
      bf16x8 t;
#pragma unroll
      for (int i=0;i<4;i++){ t[i] = f2bf_s(xa[u][0][i]); t[i+4] = f2bf_s(xa[u][1][i]); }
      xf[u] = t;
    }
#pragma unroll
    for (int mt=0;mt<4;mt++){
      bf16x8 wf = pf[(OFF_ENC + kt*4 + mt)*64 + lane];
      acc[0][mt] = MFMA(wf, xf[0], acc[0][mt]);
      acc[1][mt] = MFMA(wf, xf[1], acc[1][mt]);
    }
#pragma unroll
    for (int u=0;u<2;u++){ xa[u][0] = xn[u][0]; xa[u][1] = xn[u][1]; }
  }

  // relu+bias, stage e into LDS (row-major [16][72] bf16 per u)
#pragma unroll
  for (int mt=0;mt<4;mt++){
    f32x4 be = *(const f32x4*)(b_enc + mt*16 + g*4);
#pragma unroll
    for (int u=0;u<2;u++){
      uint2 pk;
      pk.x = pk2(fmaxf(acc[u][mt][0]+be[0],0.f), fmaxf(acc[u][mt][1]+be[1],0.f));
      pk.y = pk2(fmaxf(acc[u][mt][2]+be[2],0.f), fmaxf(acc[u][mt][3]+be[3],0.f));
      *(uint2*)(&buf[wid][u][l15*72 + mt*16 + g*4]) = pk;
    }
  }
  __threadfence_block();

  // ======== Stage O: h0 = e @ W_obs + b_obs, written to LDS as bf16 ======
  {
    bf16x8 ef[2][2];
#pragma unroll
    for (int u=0;u<2;u++)
#pragma unroll
      for (int kt=0;kt<2;kt++)
        ef[u][kt] = *(const bf16x8*)(&buf[wid][u][l15*72 + kt*32 + g*8]);
    f32x4 h0[2][4];
#pragma unroll
    for (int u=0;u<2;u++)
#pragma unroll
      for (int mt=0;mt<4;mt++) h0[u][mt] = zero4();
#pragma unroll
    for (int kt=0;kt<2;kt++)
#pragma unroll
      for (int mt=0;mt<4;mt++){
        bf16x8 wf = pf[(OFF_OBS + kt*4 + mt)*64 + lane];
        h0[0][mt] = MFMA(wf, ef[0][kt], h0[0][mt]);
        h0[1][mt] = MFMA(wf, ef[1][kt], h0[1][mt]);
      }
#pragma unroll
    for (int mt=0;mt<4;mt++){
      f32x4 bo = *(const f32x4*)(b_obs + mt*16 + g*4);
#pragma unroll
      for (int u=0;u<2;u++){
        uint2 pk;
        pk.x = pk2(h0[u][mt][0]+bo[0], h0[u][mt][1]+bo[1]);
        pk.y = pk2(h0[u][mt][2]+bo[2], h0[u][mt][3]+bo[3]);
        *(uint2*)(&buf[wid][u][l15*72 + mt*16 + g*4]) = pk;
      }
    }
  }
  __threadfence_block();

  // ======== GRU step 1 (c = 0): gi = bi; h0 re-read from LDS (bf16) ======
  {
    bf16x8 hf[2][2];
#pragma unroll
    for (int u=0;u<2;u++)
#pragma unroll
      for (int kt=0;kt<2;kt++)
        hf[u][kt] = *(const bf16x8*)(&buf[wid][u][l15*72 + kt*32 + g*8]);
#pragma unroll
    for (int mt=0;mt<4;mt++){
      f32x4 brz_r = *(const f32x4*)(bc +       mt*16 + g*4);
      f32x4 brz_z = *(const f32x4*)(bc + 64  + mt*16 + g*4);
      f32x4 bin   = *(const f32x4*)(bc + 128 + mt*16 + g*4);
      f32x4 bhn   = *(const f32x4*)(bc + 192 + mt*16 + g*4);
      f32x4 gr[2], gz[2], gn[2];
#pragma unroll
      for (int u=0;u<2;u++){ gr[u]=zero4(); gz[u]=zero4(); gn[u]=zero4(); }
#pragma unroll
      for (int kt=0;kt<2;kt++){
        bf16x8 wr_ = pf[(OFF_WH + kt*12 + mt    )*64 + lane];
        bf16x8 wz_ = pf[(OFF_WH + kt*12 + mt + 4)*64 + lane];
        bf16x8 wn_ = pf[(OFF_WH + kt*12 + mt + 8)*64 + lane];
#pragma unroll
        for (int u=0;u<2;u++){
          gr[u] = MFMA(wr_, hf[u][kt], gr[u]);
          gz[u] = MFMA(wz_, hf[u][kt], gz[u]);
          gn[u] = MFMA(wn_, hf[u][kt], gn[u]);
        }
      }
#pragma unroll
      for (int u=0;u<2;u++){
        uint2 q = *(const uint2*)(&buf[wid][u][l15*72 + mt*16 + g*4]);  // h0 bf16
        float h0v[4];
        h0v[0] = bf2f((unsigned short)(q.x & 0xffff));
        h0v[1] = bf2f((unsigned short)(q.x >> 16));
        h0v[2] = bf2f((unsigned short)(q.y & 0xffff));
        h0v[3] = bf2f((unsigned short)(q.y >> 16));
        f32x4 h1;
#pragma unroll
        for (int j=0;j<4;j++){
          float r = sigmoidf_(gr[u][j] + brz_r[j]);
          float z = sigmoidf_(gz[u][j] + brz_z[j]);
          float n = tanhf_(bin[j] + r*(gn[u][j] + bhn[j]));
          h1[j] = (1.f - z)*n + z*h0v[j];
        }
        uint2 pk;                      // overwrite with h1 (hf reads done)
        pk.x = pk2(h1[0], h1[1]);
        pk.y = pk2(h1[2], h1[3]);
        *(uint2*)(&buf[wid][u][l15*72 + mt*16 + g*4]) = pk;
      }
    }
  }
  __threadfence_block();

  // ======== agent mix: per-batch column sums -> c = (S - h1)/8 ========
#pragma unroll
  for (int u=0;u<2;u++){
    int b = lane>>5;
#pragma unroll
    for (int rep=0;rep<2;rep++){
      int c = (lane&31) + rep*32;
      float s = 0.f;
#pragma unroll
      for (int r=0;r<8;r++) s += bf2f(buf[wid][u][(b*8+r)*72 + c]);
      Sbuf[wid][u][b][c] = s;
    }
  }
  __threadfence_block();

  bf16x8 hf2[2][2], cf[2][2];
#pragma unroll
  for (int u=0;u<2;u++)
#pragma unroll
    for (int kt=0;kt<2;kt++){
      bf16x8 h8 = *(const bf16x8*)(&buf[wid][u][l15*72 + kt*32 + g*8]);
      hf2[u][kt] = h8;
      f32x4 s0 = *(const f32x4*)(&Sbuf[wid][u][l15>>3][kt*32 + g*8]);
      f32x4 s1 = *(const f32x4*)(&Sbuf[wid][u][l15>>3][kt*32 + g*8 + 4]);
      bf16x8 c8;
#pragma unroll
      for (int i=0;i<4;i++){
        c8[i]   = f2bf_s((s0[i] - bf2f((unsigned short)h8[i]  )) * 0.125f);
        c8[i+4] = f2bf_s((s1[i] - bf2f((unsigned short)h8[i+4])) * 0.125f);
      }
      cf[u][kt] = c8;
    }

  // ======== GRU step 2 + fused decode ========
  float p[2]; p[0]=0.f; p[1]=0.f;
#pragma unroll
  for (int mt=0;mt<4;mt++){
    f32x4 brz_r = *(const f32x4*)(bc +       mt*16 + g*4);
    f32x4 brz_z = *(const f32x4*)(bc + 64  + mt*16 + g*4);
    f32x4 bin   = *(const f32x4*)(bc + 128 + mt*16 + g*4);
    f32x4 bhn   = *(const f32x4*)(bc + 192 + mt*16 + g*4);
    f32x4 wdv   = *(const f32x4*)(wdec + mt*16 + g*4);
    f32x4 gr[2], gz[2], gni[2], gnh[2];
#pragma unroll
    for (int u=0;u<2;u++){ gr[u]=zero4(); gz[u]=zero4(); gni[u]=zero4(); gnh[u]=zero4(); }
#pragma unroll
    for (int kt=0;kt<2;kt++){
      bf16x8 whr = pf[(OFF_WH + kt*12 + mt    )*64 + lane];
      bf16x8 whz = pf[(OFF_WH + kt*12 + mt + 4)*64 + lane];
      bf16x8 whn = pf[(OFF_WH + kt*12 + mt + 8)*64 + lane];
      bf16x8 wir = pf[(OFF_WI + kt*12 + mt    )*64 + lane];
      bf16x8 wiz = pf[(OFF_WI + kt*12 + mt + 4)*64 + lane];
      bf16x8 win = pf[(OFF_WI + kt*12 + mt + 8)*64 + lane];
#pragma unroll
      for (int u=0;u<2;u++){
        gr[u]  = MFMA(whr, hf2[u][kt], gr[u]);
        gr[u]  = MFMA(wir, cf[u][kt],  gr[u]);
        gz[u]  = MFMA(whz, hf2[u][kt], gz[u]);
        gz[u]  = MFMA(wiz, cf[u][kt],  gz[u]);
        gnh[u] = MFMA(whn, hf2[u][kt], gnh[u]);
        gni[u] = MFMA(win, cf[u][kt],  gni[u]);
      }
    }
#pragma unroll
    for (int u=0;u<2;u++){
      uint2 q = *(const uint2*)(&buf[wid][u][l15*72 + mt*16 + g*4]);  // h1 bf16
      float h1v[4];
      h1v[0] = bf2f((unsigned short)(q.x & 0xffff));
      h1v[1] = bf2f((unsigned short)(q.x >> 16));
      h1v[2] = bf2f((unsigned short)(q.y & 0xffff));
      h1v[3] = bf2f((unsigned short)(q.y >> 16));
#pragma unroll
      for (int j=0;j<4;j++){
        float r = sigmoidf_(gr[u][j] + brz_r[j]);
        float z = sigmoidf_(gz[u][j] + brz_z[j]);
        float n = tanhf_(gni[u][j] + bin[j] + r*(gnh[u][j] + bhn[j]));
        float h2 = (1.f - z)*n + z*h1v[j];
        p[u] += h2 * wdv[j];            // fused decode
      }
    }
  }

  // ======== decode reduce + store ========
  float bd = bdec[0];
#pragma unroll
  for (int u=0;u<2;u++){
    float v = p[u];
    v += __shfl_xor(v, 16, 64);
    v += __shfl_xor(v, 32, 64);
    if (lane < 16) out[rb + u*16 + l15] = v + bd;
  }
}

// ---------------- launch ----------------
extern "C" void kernel_launch(void* const* d_in, const int* in_sizes, int n_in,
                              void* d_out, int out_size, void* d_ws, size_t ws_size,
                              hipStream_t stream) {
  (void)in_sizes; (void)n_in; (void)out_size; (void)ws_size;
  const float* obs   = (const float*)d_in[0];
  const float* act   = (const float*)d_in[1];
  const float* W_enc = (const float*)d_in[2];
  const float* b_enc = (const float*)d_in[3];
  const float* W_obs = (const float*)d_in[4];
  const float* b_obs = (const float*)d_in[5];
  const float* Wi    = (const float*)d_in[6];
  const float* bi    = (const float*)d_in[7];
  const float* Wh    = (const float*)d_in[8];
  const float* bh    = (const float*)d_in[9];
  const float* wdec  = (const float*)d_in[10];
  const float* bdec  = (const float*)d_in[11];
  unsigned short* pw = (unsigned short*)d_ws;   // 76 KiB frags + 1 KiB biases

  hipLaunchKernelGGL(pack_weights, dim3(NFRAG+1), dim3(64), 0, stream,
                     W_enc, W_obs, Wi, Wh, bi, bh, pw);
  hipLaunchKernelGGL(critic_main, dim3(NROW/128), dim3(256), 0, stream,
                     obs, act, b_enc, b_obs, wdec, bdec, pw, (float*)d_out);
}